// Round 2
// baseline (572.297 us; speedup 1.0000x reference)
//
#include <hip/hip_runtime.h>
#include <hip/hip_bf16.h>

#define B_    2
#define S_    2048
#define H_    15
#define KVH_  5
#define G_    3
#define D_    64
#define KVD_  (KVH_ * D_)      // 320
#define HD_   (H_ * D_)        // 960
#define SW_   (S_ / 32)        // 64 mask words per row

constexpr float SCALE   = 0.125f;      // 64^-0.5
constexpr float NEG_BIG = -3.0e38f;

typedef __bf16  bf16x8 __attribute__((ext_vector_type(8)));
typedef __bf16  bf16x4 __attribute__((ext_vector_type(4)));
typedef float   f32x4  __attribute__((ext_vector_type(4)));

#define MFMA(a, b, c) __builtin_amdgcn_mfma_f32_16x16x32_bf16((a), (b), (c), 0, 0, 0)

// ---------------- pre-pass 1: mask (int32 0/1) -> bitmask ----------------
__global__ __launch_bounds__(256) void bitpack(const int* __restrict__ mask,
                                               unsigned int* __restrict__ bits) {
    const int i = blockIdx.x * 256 + threadIdx.x;          // over B*S*S
    unsigned long long bal = __ballot(mask[i] != 0);
    const int lane = threadIdx.x & 63;
    if (lane == 0)       bits[i >> 5] = (unsigned int)bal;
    else if (lane == 32) bits[i >> 5] = (unsigned int)(bal >> 32);
}

// ---------------- pre-pass 2: K fp32 -> bf16 hi/lo (same layout) ----------------
__global__ __launch_bounds__(256) void conv_k(const float* __restrict__ K,
                                              __bf16* __restrict__ khi,
                                              __bf16* __restrict__ klo) {
    const int i = blockIdx.x * 256 + threadIdx.x;          // over (B*S*KVH*D)/4
    const float4 v = ((const float4*)K)[i];
    const float xs[4] = {v.x, v.y, v.z, v.w};
    bf16x4 h, lo;
#pragma unroll
    for (int j = 0; j < 4; j++) {
        __bf16 hh = (__bf16)xs[j];
        h[j]  = hh;
        lo[j] = (__bf16)(xs[j] - (float)hh);
    }
    ((bf16x4*)khi)[i] = h;
    ((bf16x4*)klo)[i] = lo;
}

// ---------------- pre-pass 3: V fp32 [B,S,KVH,D] -> bf16 hi/lo transposed [B,KVH,D,S] ----------------
__global__ __launch_bounds__(256) void transpose_v(const float* __restrict__ V,
                                                   __bf16* __restrict__ vthi,
                                                   __bf16* __restrict__ vtlo) {
    __shared__ float tile[64][65];
    const int bid = blockIdx.x;                 // B*KVH*(S/64)
    const int st  = bid & 31;
    const int kv  = (bid >> 5) % KVH_;
    const int b   = bid / (32 * KVH_);
    const int s0  = st * 64;
    const int tid = threadIdx.x;
    const int c   = tid & 63;
    const int rq  = tid >> 6;                   // 0..3
#pragma unroll
    for (int i = 0; i < 16; i++) {
        const int si = rq + i * 4;
        tile[si][c] = V[(((size_t)b * S_ + s0 + si) * KVH_ + kv) * D_ + c];
    }
    __syncthreads();
#pragma unroll
    for (int i = 0; i < 16; i++) {
        const int di = rq + i * 4;              // d index
        const float x = tile[c][di];            // s index = c
        const __bf16 hh = (__bf16)x;
        const size_t o = (((size_t)b * KVH_ + kv) * D_ + di) * S_ + s0 + c;
        vthi[o] = hh;
        vtlo[o] = (__bf16)(x - (float)hh);
    }
}

// ---------------- main flash-attention kernel ----------------
// grid: B*H*(S/64) blocks of 256 (4 waves); wave w handles 16 q rows.
__global__ __launch_bounds__(256) void attn_main(const unsigned int* __restrict__ bits,
                                                 const float* __restrict__ Q,
                                                 const __bf16* __restrict__ khi,
                                                 const __bf16* __restrict__ klo,
                                                 const __bf16* __restrict__ vthi,
                                                 const __bf16* __restrict__ vtlo,
                                                 float* __restrict__ out) {
    __shared__ float sm[4][16][68];             // per-wave P tile, fp32, padded (+4 keeps 16B align, 2-way banks)

    const int tid  = threadIdx.x;
    const int wv   = tid >> 6;
    const int lane = tid & 63;
    const int lrow = lane & 15;
    const int lgrp = lane >> 4;

    const int bid = blockIdx.x;
    const int qt  = bid & 31;                   // S/64 = 32 q-tiles
    const int bh  = bid >> 5;
    const int h   = bh % H_;
    const int b   = bh / H_;
    const int kv  = h / G_;
    const int q0  = qt * 64 + wv * 16;

    // ---- Q fragments (A operand: row = lane&15, k-elems = lgrp*8+j, +32 per kk) ----
    const float* qp = Q + (((size_t)b * S_ + (q0 + lrow)) * H_ + h) * D_;
    bf16x8 ahi[2], alo[2];
#pragma unroll
    for (int kk = 0; kk < 2; kk++) {
#pragma unroll
        for (int jj = 0; jj < 2; jj++) {
            const float4 v = *(const float4*)(qp + kk * 32 + lgrp * 8 + jj * 4);
            const float xs[4] = {v.x, v.y, v.z, v.w};
#pragma unroll
            for (int j = 0; j < 4; j++) {
                const __bf16 hh = (__bf16)xs[j];
                ahi[kk][jj * 4 + j] = hh;
                alo[kk][jj * 4 + j] = (__bf16)(xs[j] - (float)hh);
            }
        }
    }

    f32x4 O[4] = {{0.f,0.f,0.f,0.f},{0.f,0.f,0.f,0.f},{0.f,0.f,0.f,0.f},{0.f,0.f,0.f,0.f}};
    float m[4], l[4];
#pragma unroll
    for (int r = 0; r < 4; r++) { m[r] = NEG_BIG; l[r] = 0.f; }

    const __bf16* khb = khi + (size_t)b * S_ * KVD_ + kv * D_;
    const __bf16* klb = klo + (size_t)b * S_ * KVD_ + kv * D_;
    const __bf16* vhb = vthi + ((size_t)b * KVH_ + kv) * D_ * S_;
    const __bf16* vlb = vtlo + ((size_t)b * KVH_ + kv) * D_ * S_;
    const unsigned int* bitsb = bits + ((size_t)b * S_ + q0 + lgrp * 4) * SW_;

    for (int kt = 0; kt < 32; kt++) {
        const int k0 = kt * 64;

        // ---- QK^T: 4 tiles of 16 keys ----
        f32x4 s[4];
#pragma unroll
        for (int t = 0; t < 4; t++) {
            const __bf16* kph = khb + (size_t)(k0 + t * 16 + lrow) * KVD_;
            const __bf16* kpl = klb + (size_t)(k0 + t * 16 + lrow) * KVD_;
            const bf16x8 bh0 = *(const bf16x8*)(kph + lgrp * 8);
            const bf16x8 bh1 = *(const bf16x8*)(kph + 32 + lgrp * 8);
            const bf16x8 bl0 = *(const bf16x8*)(kpl + lgrp * 8);
            const bf16x8 bl1 = *(const bf16x8*)(kpl + 32 + lgrp * 8);
            f32x4 acc = {0.f, 0.f, 0.f, 0.f};
            acc = MFMA(ahi[0], bh0, acc);
            acc = MFMA(alo[0], bh0, acc);
            acc = MFMA(ahi[0], bl0, acc);
            acc = MFMA(ahi[1], bh1, acc);
            acc = MFMA(alo[1], bh1, acc);
            acc = MFMA(ahi[1], bl1, acc);
            s[t] = acc;
        }

        // ---- mask + scale + online softmax (C layout: row=(lane>>4)*4+r, col=lane&15) ----
        float fr[4];
#pragma unroll
        for (int r = 0; r < 4; r++) {
            const unsigned int* brow = bitsb + (size_t)r * SW_ + (k0 >> 5);
            const unsigned int w0 = brow[0], w1 = brow[1];
            float tm = NEG_BIG;
#pragma unroll
            for (int t = 0; t < 4; t++) {
                const unsigned int w = (t < 2) ? w0 : w1;
                const int bit = (t * 16 + lrow) & 31;
                const float sv = ((w >> bit) & 1u) ? s[t][r] * SCALE : NEG_BIG;
                s[t][r] = sv;
                tm = fmaxf(tm, sv);
            }
            tm = fmaxf(tm, __shfl_xor(tm, 1));
            tm = fmaxf(tm, __shfl_xor(tm, 2));
            tm = fmaxf(tm, __shfl_xor(tm, 4));
            tm = fmaxf(tm, __shfl_xor(tm, 8));
            const float mn = fmaxf(m[r], tm);
            const float f  = __expf(m[r] - mn);
            m[r] = mn;
            l[r] *= f;
            fr[r] = f;
            float ps = 0.f;
#pragma unroll
            for (int t = 0; t < 4; t++) {
                const float p = __expf(s[t][r] - mn);
                ps += p;
                sm[wv][lgrp * 4 + r][t * 16 + lrow] = p;
            }
            l[r] += ps;
        }
#pragma unroll
        for (int db = 0; db < 4; db++) {
            f32x4 o = O[db];
            o[0] *= fr[0]; o[1] *= fr[1]; o[2] *= fr[2]; o[3] *= fr[3];
            O[db] = o;
        }
        __syncthreads();

        // ---- PV: P (16x64, from LDS) x V^T-layout (d-major) ----
#pragma unroll
        for (int kk = 0; kk < 2; kk++) {
            bf16x8 ph, pl;
#pragma unroll
            for (int j = 0; j < 8; j++) {
                const float p = sm[wv][lrow][kk * 32 + lgrp * 8 + j];
                const __bf16 hh = (__bf16)p;
                ph[j] = hh;
                pl[j] = (__bf16)(p - (float)hh);
            }
#pragma unroll
            for (int db = 0; db < 4; db++) {
                const size_t voff = (size_t)(db * 16 + lrow) * S_ + k0 + kk * 32 + lgrp * 8;
                const bf16x8 vh = *(const bf16x8*)(vhb + voff);
                const bf16x8 vl = *(const bf16x8*)(vlb + voff);
                O[db] = MFMA(ph, vh, O[db]);
                O[db] = MFMA(pl, vh, O[db]);
                O[db] = MFMA(ph, vl, O[db]);
            }
        }
        __syncthreads();
    }

    // ---- epilogue: reduce l across the 16-lane column groups, normalize, store ----
#pragma unroll
    for (int r = 0; r < 4; r++) {
        float lv = l[r];
        lv += __shfl_xor(lv, 1);
        lv += __shfl_xor(lv, 2);
        lv += __shfl_xor(lv, 4);
        lv += __shfl_xor(lv, 8);
        l[r] = 1.0f / lv;
    }
#pragma unroll
    for (int db = 0; db < 4; db++) {
#pragma unroll
        for (int r = 0; r < 4; r++) {
            const int q = q0 + lgrp * 4 + r;
            out[((size_t)b * S_ + q) * HD_ + h * D_ + db * 16 + lrow] = O[db][r] * l[r];
        }
    }
}

extern "C" void kernel_launch(void* const* d_in, const int* in_sizes, int n_in,
                              void* d_out, int out_size, void* d_ws, size_t ws_size,
                              hipStream_t stream) {
    const int*   mask = (const int*)d_in[0];
    const float* Q    = (const float*)d_in[1];
    const float* K    = (const float*)d_in[2];
    const float* V    = (const float*)d_in[3];
    float*       out  = (float*)d_out;

    char* ws = (char*)d_ws;
    // layout: bits 1MB | khi 2.5MB | klo 2.5MB | vthi 2.5MB | vtlo 2.5MB  (total ~11MB)
    unsigned int* bits = (unsigned int*)ws;
    const size_t KV_BYTES = (size_t)B_ * S_ * KVH_ * D_ * sizeof(__bf16);   // 2,621,440
    __bf16* khi  = (__bf16*)(ws + (1 << 20));
    __bf16* klo  = (__bf16*)(ws + (1 << 20) + KV_BYTES);
    __bf16* vthi = (__bf16*)(ws + (1 << 20) + 2 * KV_BYTES);
    __bf16* vtlo = (__bf16*)(ws + (1 << 20) + 3 * KV_BYTES);

    bitpack<<<(B_ * S_ * S_) / 256, 256, 0, stream>>>(mask, bits);
    conv_k<<<(B_ * S_ * KVH_ * D_) / (256 * 4), 256, 0, stream>>>(K, khi, klo);
    transpose_v<<<B_ * KVH_ * (S_ / 64), 256, 0, stream>>>(V, vthi, vtlo);
    attn_main<<<B_ * H_ * (S_ / 64), 256, 0, stream>>>(bits, Q, khi, klo, vthi, vtlo, out);
}

// Round 5
// 302.660 us; speedup vs baseline: 1.8909x; 1.8909x over previous
//
#include <hip/hip_runtime.h>
#include <hip/hip_bf16.h>

#define B_    2
#define S_    2048
#define H_    15
#define KVH_  5
#define G_    3
#define D_    64
#define KVD_  (KVH_ * D_)      // 320
#define HD_   (H_ * D_)        // 960
#define SW_   (S_ / 32)        // 64 mask words per row
#define KBLK  32
#define ITER  (S_ / KBLK)      // 64

constexpr float SCALE   = 0.125f;      // 64^-0.5
constexpr float NEG_BIG = -3.0e38f;

typedef __bf16  bf16x8 __attribute__((ext_vector_type(8)));
typedef __bf16  bf16x4 __attribute__((ext_vector_type(4)));
typedef float   f32x4  __attribute__((ext_vector_type(4)));

#define MFMA(a, b, c) __builtin_amdgcn_mfma_f32_16x16x32_bf16((a), (b), (c), 0, 0, 0)

// async global->LDS, 16B per lane; LDS dest is wave-uniform base, lane i lands at base+i*16
__device__ __forceinline__ void gload16(const void* g, void* l) {
    __builtin_amdgcn_global_load_lds(
        (const __attribute__((address_space(1))) unsigned int*)g,
        (__attribute__((address_space(3))) unsigned int*)l, 16, 0, 0);
}

// ---------------- pre-pass 1: mask (int32 0/1) -> bitmask ----------------
__global__ __launch_bounds__(256) void bitpack(const int* __restrict__ mask,
                                               unsigned int* __restrict__ bits) {
    const int i = blockIdx.x * 256 + threadIdx.x;          // over B*S*S
    unsigned long long bal = __ballot(mask[i] != 0);
    const int lane = threadIdx.x & 63;
    if (lane == 0)       bits[i >> 5] = (unsigned int)bal;
    else if (lane == 32) bits[i >> 5] = (unsigned int)(bal >> 32);
}

// ---------------- pre-pass 2: K fp32 -> bf16 hi/lo (same layout) ----------------
__global__ __launch_bounds__(256) void conv_k(const float* __restrict__ K,
                                              __bf16* __restrict__ khi,
                                              __bf16* __restrict__ klo) {
    const int i = blockIdx.x * 256 + threadIdx.x;          // over (B*S*KVH*D)/4
    const float4 v = ((const float4*)K)[i];
    const float xs[4] = {v.x, v.y, v.z, v.w};
    bf16x4 h, lo;
#pragma unroll
    for (int j = 0; j < 4; j++) {
        __bf16 hh = (__bf16)xs[j];
        h[j]  = hh;
        lo[j] = (__bf16)(xs[j] - (float)hh);
    }
    ((bf16x4*)khi)[i] = h;
    ((bf16x4*)klo)[i] = lo;
}

// ---------------- pre-pass 3: V fp32 [B,S,KVH,D] -> bf16 hi/lo transposed [B,KVH,D,S] ----------------
__global__ __launch_bounds__(256) void transpose_v(const float* __restrict__ V,
                                                   __bf16* __restrict__ vthi,
                                                   __bf16* __restrict__ vtlo) {
    __shared__ float tile[64][65];
    const int bid = blockIdx.x;                 // B*KVH*(S/64)
    const int st  = bid & 31;
    const int kv  = (bid >> 5) % KVH_;
    const int b   = bid / (32 * KVH_);
    const int s0  = st * 64;
    const int tid = threadIdx.x;
    const int c   = tid & 63;
    const int rq  = tid >> 6;                   // 0..3
#pragma unroll
    for (int i = 0; i < 16; i++) {
        const int si = rq + i * 4;
        tile[si][c] = V[(((size_t)b * S_ + s0 + si) * KVH_ + kv) * D_ + c];
    }
    __syncthreads();
#pragma unroll
    for (int i = 0; i < 16; i++) {
        const int di = rq + i * 4;              // d index
        const float x = tile[c][di];            // s index = c
        const __bf16 hh = (__bf16)x;
        const size_t o = (((size_t)b * KVH_ + kv) * D_ + di) * S_ + s0 + c;
        vthi[o] = hh;
        vtlo[o] = (__bf16)(x - (float)hh);
    }
}

// ---------------- main flash-attention kernel ----------------
// grid: B*H*(S/64) blocks of 256 (4 waves); wave w handles 16 q rows, KBLK=32 keys/iter.
// K double-buffered LDS (prefetch kt+1), V single-buffered (staged at phase start, consumed
// after barrier1), P through LDS. XOR-swizzled layouts (inverse swizzle on global src).
__global__ __launch_bounds__(256) void attn_main(const unsigned int* __restrict__ bits,
                                                 const float* __restrict__ Q,
                                                 const __bf16* __restrict__ khi,
                                                 const __bf16* __restrict__ klo,
                                                 const __bf16* __restrict__ vthi,
                                                 const __bf16* __restrict__ vtlo,
                                                 float* __restrict__ out) {
    // K: [buf][hi/lo][key 0..31][d 0..63]  row=128B=8 granules, LDS[r][g]=global[r][g^(r&7)]
    // V: [hi/lo][d 0..63][key 0..31]       row=64B =4 granules, LDS[r][g]=global[r][g^((r>>1)&3)]
    // P: [wave][qrow 0..15][key 0..31 +pad]
    __shared__ __align__(16) __bf16 Kls[2][2][KBLK][64];   // 16 KB
    __shared__ __align__(16) __bf16 Vls[2][64][KBLK];      //  8 KB
    __shared__ __align__(16) float  Pls[4][16][36];        //  9 KB

    const int tid  = threadIdx.x;
    const int wv   = tid >> 6;
    const int lane = tid & 63;
    const int lrow = lane & 15;
    const int lgrp = lane >> 4;

    const int bid = blockIdx.x;
    const int qt  = bid & 31;                   // 32 q-tiles of 64
    const int bh  = bid >> 5;
    const int h   = bh % H_;
    const int b   = bh / H_;
    const int kv  = h / G_;
    const int q0  = qt * 64 + wv * 16;

    // ---- Q fragments ----
    const float* qp = Q + (((size_t)b * S_ + (q0 + lrow)) * H_ + h) * D_;
    bf16x8 ahi[2], alo[2];
#pragma unroll
    for (int kk = 0; kk < 2; kk++) {
#pragma unroll
        for (int jj = 0; jj < 2; jj++) {
            const float4 v = *(const float4*)(qp + kk * 32 + lgrp * 8 + jj * 4);
            const float xs[4] = {v.x, v.y, v.z, v.w};
#pragma unroll
            for (int j = 0; j < 4; j++) {
                const __bf16 hh = (__bf16)xs[j];
                ahi[kk][jj * 4 + j] = hh;
                alo[kk][jj * 4 + j] = (__bf16)(xs[j] - (float)hh);
            }
        }
    }

    f32x4 O[4] = {{0.f,0.f,0.f,0.f},{0.f,0.f,0.f,0.f},{0.f,0.f,0.f,0.f},{0.f,0.f,0.f,0.f}};
    float m[4], l[4];
#pragma unroll
    for (int r = 0; r < 4; r++) { m[r] = NEG_BIG; l[r] = 0.f; }

    const __bf16* khb = khi + (size_t)b * S_ * KVD_ + kv * D_;
    const __bf16* klb = klo + (size_t)b * S_ * KVD_ + kv * D_;
    const __bf16* vhb = vthi + ((size_t)b * KVH_ + kv) * D_ * S_;
    const __bf16* vlb = vtlo + ((size_t)b * KVH_ + kv) * D_ * S_;
    const unsigned int* bitsb = bits + ((size_t)b * S_ + q0 + lgrp * 4) * SW_;

    // staging geometry: per gload16 a wave covers 64 granules of 16B.
    // K rows are 8 granules wide -> wave covers 8 rows -> LDS base row = wv*8.
    // V rows are 4 granules wide -> wave covers 16 rows -> LDS base row = wv*16.
    const int kgi  = wv * 64 + lane;            // K granule id over [key 0..31][gran 0..7]
    const int krow = kgi >> 3, kcg = kgi & 7;
    const int kcol = ((kcg ^ (krow & 7)) * 8);  // inverse-swizzled global d-offset
    const int vrow = kgi >> 2, vcg = kgi & 3;   // V granule id over [d 0..63][gran 0..3]
    const int vcol = ((vcg ^ ((vrow >> 1) & 3)) * 8); // inverse-swizzled global key-offset

    // prologue: stage K tile 0 into buf 0
    gload16(khb + (size_t)krow * KVD_ + kcol, &Kls[0][0][wv * 8][0]);
    gload16(klb + (size_t)krow * KVD_ + kcol, &Kls[0][1][wv * 8][0]);
    __syncthreads();

    for (int kt = 0; kt < ITER; kt++) {
        const int k0  = kt * KBLK;
        const int cur = kt & 1;

        // ---- phase A: issue prefetches, then compute QK^T + softmax ----
        unsigned bw[4];
#pragma unroll
        for (int r = 0; r < 4; r++) bw[r] = bitsb[(size_t)r * SW_ + kt];

        if (kt + 1 < ITER) {
            const size_t koff = (size_t)(k0 + KBLK + krow) * KVD_ + kcol;
            gload16(khb + koff, &Kls[cur ^ 1][0][wv * 8][0]);
            gload16(klb + koff, &Kls[cur ^ 1][1][wv * 8][0]);
        }
        {
            const size_t voff = (size_t)vrow * S_ + k0 + vcol;
            gload16(vhb + voff, &Vls[0][wv * 16][0]);
            gload16(vlb + voff, &Vls[1][wv * 16][0]);
        }

        // QK^T: 2 tiles of 16 keys from swizzled K-LDS
        f32x4 s[2];
#pragma unroll
        for (int t = 0; t < 2; t++) {
            const int row = t * 16 + lrow;
            const int sw  = row & 7;
            const bf16x8 bh0 = *(const bf16x8*)&Kls[cur][0][row][(lgrp ^ sw) * 8];
            const bf16x8 bh1 = *(const bf16x8*)&Kls[cur][0][row][((4 + lgrp) ^ sw) * 8];
            const bf16x8 bl0 = *(const bf16x8*)&Kls[cur][1][row][(lgrp ^ sw) * 8];
            const bf16x8 bl1 = *(const bf16x8*)&Kls[cur][1][row][((4 + lgrp) ^ sw) * 8];
            f32x4 acc = {0.f, 0.f, 0.f, 0.f};
            acc = MFMA(ahi[0], bh0, acc);
            acc = MFMA(alo[0], bh0, acc);
            acc = MFMA(ahi[0], bl0, acc);
            acc = MFMA(ahi[1], bh1, acc);
            acc = MFMA(alo[1], bh1, acc);
            acc = MFMA(ahi[1], bl1, acc);
            s[t] = acc;
        }

        // mask + scale + online softmax (C layout: row(q)=lgrp*4+r, col(key)=lrow)
        float fr_[4];
#pragma unroll
        for (int r = 0; r < 4; r++) {
            const unsigned w = bw[r];
            float sv0 = ((w >> lrow) & 1u)        ? s[0][r] * SCALE : NEG_BIG;
            float sv1 = ((w >> (16 + lrow)) & 1u) ? s[1][r] * SCALE : NEG_BIG;
            float tm = fmaxf(sv0, sv1);
            tm = fmaxf(tm, __shfl_xor(tm, 1));
            tm = fmaxf(tm, __shfl_xor(tm, 2));
            tm = fmaxf(tm, __shfl_xor(tm, 4));
            tm = fmaxf(tm, __shfl_xor(tm, 8));
            const float mn = fmaxf(m[r], tm);
            const float f  = __expf(m[r] - mn);
            m[r] = mn;
            l[r] *= f;
            fr_[r] = f;
            const float p0 = __expf(sv0 - mn);
            const float p1 = __expf(sv1 - mn);
            l[r] += p0 + p1;
            Pls[wv][lgrp * 4 + r][lrow]      = p0;
            Pls[wv][lgrp * 4 + r][16 + lrow] = p1;
        }
#pragma unroll
        for (int db = 0; db < 4; db++) {
            f32x4 o = O[db];
            o[0] *= fr_[0]; o[1] *= fr_[1]; o[2] *= fr_[2]; o[3] *= fr_[3];
            O[db] = o;
        }
        __syncthreads();   // drains vmcnt: V(kt) + K(kt+1) staged; P visible

        // ---- phase C: PV from P-LDS + swizzled V-LDS ----
        const f32x4 pa = *(const f32x4*)&Pls[wv][lrow][lgrp * 8];
        const f32x4 pb = *(const f32x4*)&Pls[wv][lrow][lgrp * 8 + 4];
        bf16x8 ph, pl;
#pragma unroll
        for (int j = 0; j < 4; j++) {
            const __bf16 ha = (__bf16)pa[j];
            const __bf16 hb = (__bf16)pb[j];
            ph[j]     = ha;
            ph[4 + j] = hb;
            pl[j]     = (__bf16)(pa[j] - (float)ha);
            pl[4 + j] = (__bf16)(pb[j] - (float)hb);
        }
#pragma unroll
        for (int db = 0; db < 4; db++) {
            const int row = db * 16 + lrow;
            const int sw  = (row >> 1) & 3;
            const bf16x8 vh = *(const bf16x8*)&Vls[0][row][(lgrp ^ sw) * 8];
            const bf16x8 vl = *(const bf16x8*)&Vls[1][row][(lgrp ^ sw) * 8];
            O[db] = MFMA(ph, vh, O[db]);
            O[db] = MFMA(pl, vh, O[db]);
            O[db] = MFMA(ph, vl, O[db]);
        }
        __syncthreads();   // Vls/Pls safe to overwrite next iteration
    }

    // ---- epilogue: reduce l across key-lanes, normalize, store ----
#pragma unroll
    for (int r = 0; r < 4; r++) {
        float lv = l[r];
        lv += __shfl_xor(lv, 1);
        lv += __shfl_xor(lv, 2);
        lv += __shfl_xor(lv, 4);
        lv += __shfl_xor(lv, 8);
        l[r] = 1.0f / lv;
    }
#pragma unroll
    for (int db = 0; db < 4; db++) {
#pragma unroll
        for (int r = 0; r < 4; r++) {
            const int q = q0 + lgrp * 4 + r;
            out[((size_t)b * S_ + q) * HD_ + h * D_ + db * 16 + lrow] = O[db][r] * l[r];
        }
    }
}

extern "C" void kernel_launch(void* const* d_in, const int* in_sizes, int n_in,
                              void* d_out, int out_size, void* d_ws, size_t ws_size,
                              hipStream_t stream) {
    const int*   mask = (const int*)d_in[0];
    const float* Q    = (const float*)d_in[1];
    const float* K    = (const float*)d_in[2];
    const float* V    = (const float*)d_in[3];
    float*       out  = (float*)d_out;

    char* ws = (char*)d_ws;
    unsigned int* bits = (unsigned int*)ws;
    const size_t KV_BYTES = (size_t)B_ * S_ * KVH_ * D_ * sizeof(__bf16);   // 2,621,440
    __bf16* khi  = (__bf16*)(ws + (1 << 20));
    __bf16* klo  = (__bf16*)(ws + (1 << 20) + KV_BYTES);
    __bf16* vthi = (__bf16*)(ws + (1 << 20) + 2 * KV_BYTES);
    __bf16* vtlo = (__bf16*)(ws + (1 << 20) + 3 * KV_BYTES);

    bitpack<<<(B_ * S_ * S_) / 256, 256, 0, stream>>>(mask, bits);
    conv_k<<<(B_ * S_ * KVH_ * D_) / (256 * 4), 256, 0, stream>>>(K, khi, klo);
    transpose_v<<<B_ * KVH_ * (S_ / 64), 256, 0, stream>>>(V, vthi, vtlo);
    attn_main<<<B_ * H_ * (S_ / 64), 256, 0, stream>>>(bits, Q, khi, klo, vthi, vtlo, out);
}

// Round 6
// 261.597 us; speedup vs baseline: 2.1877x; 1.1570x over previous
//
#include <hip/hip_runtime.h>
#include <hip/hip_bf16.h>

#define B_    2
#define S_    2048
#define H_    15
#define KVH_  5
#define G_    3
#define D_    64
#define KVD_  (KVH_ * D_)      // 320
#define HD_   (H_ * D_)        // 960
#define SW_   (S_ / 32)        // 64 mask words per row
#define KBLK  32
#define ITER  (S_ / KBLK)      // 64

constexpr float SCALE   = 0.125f;      // 64^-0.5
constexpr float NEG_BIG = -3.0e38f;
constexpr float DEFER_THR = 8.0f;      // defer-max rescale threshold (T13)

typedef __bf16  bf16x8 __attribute__((ext_vector_type(8)));
typedef __bf16  bf16x4 __attribute__((ext_vector_type(4)));
typedef float   f32x4  __attribute__((ext_vector_type(4)));
typedef int     i32x4  __attribute__((ext_vector_type(4)));

#define MFMA(a, b, c) __builtin_amdgcn_mfma_f32_16x16x32_bf16((a), (b), (c), 0, 0, 0)

// async global->LDS, 16B per lane; LDS dest is wave-uniform base, lane i lands at base+i*16
__device__ __forceinline__ void gload16(const void* g, void* l) {
    __builtin_amdgcn_global_load_lds(
        (const __attribute__((address_space(1))) unsigned int*)g,
        (__attribute__((address_space(3))) unsigned int*)l, 16, 0, 0);
}

// pack top-16-bits of two f32 into one bf16x2 word (truncation split, int-only)
__device__ __forceinline__ unsigned pack_hi16(unsigned lo_elem, unsigned hi_elem) {
    return __builtin_amdgcn_perm(hi_elem, lo_elem, 0x07060302u);
}

// ---------------- pre-pass 1: mask (int32 0/1) -> bitmask ----------------
__global__ __launch_bounds__(256) void bitpack(const int* __restrict__ mask,
                                               unsigned int* __restrict__ bits) {
    const int i = blockIdx.x * 256 + threadIdx.x;          // over B*S*S
    unsigned long long bal = __ballot(mask[i] != 0);
    const int lane = threadIdx.x & 63;
    if (lane == 0)       bits[i >> 5] = (unsigned int)bal;
    else if (lane == 32) bits[i >> 5] = (unsigned int)(bal >> 32);
}

// ---------------- pre-pass 2: K fp32 -> bf16 hi/lo (same layout) ----------------
__global__ __launch_bounds__(256) void conv_k(const float* __restrict__ K,
                                              __bf16* __restrict__ khi,
                                              __bf16* __restrict__ klo) {
    const int i = blockIdx.x * 256 + threadIdx.x;          // over (B*S*KVH*D)/4
    const float4 v = ((const float4*)K)[i];
    const float xs[4] = {v.x, v.y, v.z, v.w};
    bf16x4 h, lo;
#pragma unroll
    for (int j = 0; j < 4; j++) {
        __bf16 hh = (__bf16)xs[j];
        h[j]  = hh;
        lo[j] = (__bf16)(xs[j] - (float)hh);
    }
    ((bf16x4*)khi)[i] = h;
    ((bf16x4*)klo)[i] = lo;
}

// ---------------- pre-pass 3: V fp32 [B,S,KVH,D] -> bf16 hi/lo transposed [B,KVH,D,S] ----------------
__global__ __launch_bounds__(256) void transpose_v(const float* __restrict__ V,
                                                   __bf16* __restrict__ vthi,
                                                   __bf16* __restrict__ vtlo) {
    __shared__ float tile[64][65];
    const int bid = blockIdx.x;                 // B*KVH*(S/64)
    const int st  = bid & 31;
    const int kv  = (bid >> 5) % KVH_;
    const int b   = bid / (32 * KVH_);
    const int s0  = st * 64;
    const int tid = threadIdx.x;
    const int c   = tid & 63;
    const int rq  = tid >> 6;                   // 0..3
#pragma unroll
    for (int i = 0; i < 16; i++) {
        const int si = rq + i * 4;
        tile[si][c] = V[(((size_t)b * S_ + s0 + si) * KVH_ + kv) * D_ + c];
    }
    __syncthreads();
#pragma unroll
    for (int i = 0; i < 16; i++) {
        const int di = rq + i * 4;              // d index
        const float x = tile[c][di];            // s index = c
        const __bf16 hh = (__bf16)x;
        const size_t o = (((size_t)b * KVH_ + kv) * D_ + di) * S_ + s0 + c;
        vthi[o] = hh;
        vtlo[o] = (__bf16)(x - (float)hh);
    }
}

// ---------------- main flash-attention kernel ----------------
// grid: B*H*(S/64) blocks of 256 (4 waves); wave w handles 16 q rows, KBLK=32 keys/iter.
// K double-buffered LDS (prefetch kt+1), V single-buffered, P through LDS.
// XOR-swizzled layouts (inverse swizzle on global src). Defer-max softmax (THR=8).
__global__ __launch_bounds__(256) void attn_main(const unsigned int* __restrict__ bits,
                                                 const float* __restrict__ Q,
                                                 const __bf16* __restrict__ khi,
                                                 const __bf16* __restrict__ klo,
                                                 const __bf16* __restrict__ vthi,
                                                 const __bf16* __restrict__ vtlo,
                                                 float* __restrict__ out) {
    // K: [buf][hi/lo][key 0..31][d 0..63]  row=128B=8 granules, LDS[r][g]=global[r][g^(r&7)]
    // V: [hi/lo][d 0..63][key 0..31]       row=64B =4 granules, LDS[r][g]=global[r][g^((r>>1)&3)]
    // P: [wave][qrow 0..15][key 0..31 +pad]
    __shared__ __align__(16) __bf16 Kls[2][2][KBLK][64];   // 16 KB
    __shared__ __align__(16) __bf16 Vls[2][64][KBLK];      //  8 KB
    __shared__ __align__(16) float  Pls[4][16][36];        //  9 KB

    const int tid  = threadIdx.x;
    const int wv   = tid >> 6;
    const int lane = tid & 63;
    const int lrow = lane & 15;
    const int lgrp = lane >> 4;

    const int bid = blockIdx.x;
    const int qt  = bid & 31;                   // 32 q-tiles of 64
    const int bh  = bid >> 5;
    const int h   = bh % H_;
    const int b   = bh / H_;
    const int kv  = h / G_;
    const int q0  = qt * 64 + wv * 16;

    // ---- Q fragments ----
    const float* qp = Q + (((size_t)b * S_ + (q0 + lrow)) * H_ + h) * D_;
    bf16x8 ahi[2], alo[2];
#pragma unroll
    for (int kk = 0; kk < 2; kk++) {
#pragma unroll
        for (int jj = 0; jj < 2; jj++) {
            const float4 v = *(const float4*)(qp + kk * 32 + lgrp * 8 + jj * 4);
            const float xs[4] = {v.x, v.y, v.z, v.w};
#pragma unroll
            for (int j = 0; j < 4; j++) {
                const __bf16 hh = (__bf16)xs[j];
                ahi[kk][jj * 4 + j] = hh;
                alo[kk][jj * 4 + j] = (__bf16)(xs[j] - (float)hh);
            }
        }
    }

    f32x4 O[4] = {{0.f,0.f,0.f,0.f},{0.f,0.f,0.f,0.f},{0.f,0.f,0.f,0.f},{0.f,0.f,0.f,0.f}};
    float m[4], l[4];
#pragma unroll
    for (int r = 0; r < 4; r++) { m[r] = NEG_BIG; l[r] = 0.f; }

    const __bf16* khb = khi + (size_t)b * S_ * KVD_ + kv * D_;
    const __bf16* klb = klo + (size_t)b * S_ * KVD_ + kv * D_;
    const __bf16* vhb = vthi + ((size_t)b * KVH_ + kv) * D_ * S_;
    const __bf16* vlb = vtlo + ((size_t)b * KVH_ + kv) * D_ * S_;

    // staging geometry: per gload16 a wave covers 64 granules of 16B.
    // K rows are 8 granules wide -> wave covers 8 rows -> LDS base row = wv*8.
    // V rows are 4 granules wide -> wave covers 16 rows -> LDS base row = wv*16.
    const int kgi  = wv * 64 + lane;            // K granule id over [key 0..31][gran 0..7]
    const int krow = kgi >> 3, kcg = kgi & 7;
    const int kcol = ((kcg ^ (krow & 7)) * 8);  // inverse-swizzled global d-offset
    const int vrow = kgi >> 2, vcg = kgi & 3;   // V granule id over [d 0..63][gran 0..3]
    const int vcol = ((vcg ^ ((vrow >> 1) & 3)) * 8); // inverse-swizzled global key-offset

    // running source pointers (incremented per iter; avoids 64-bit recompute)
    const __bf16* khsrc = khb + (size_t)krow * KVD_ + kcol;
    const __bf16* klsrc = klb + (size_t)krow * KVD_ + kcol;
    const __bf16* vhsrc = vhb + (size_t)vrow * S_ + vcol;
    const __bf16* vlsrc = vlb + (size_t)vrow * S_ + vcol;
    const unsigned int* bptr = bits + ((size_t)b * S_ + q0 + lgrp * 4) * SW_;

    // prologue: stage K tile 0 into buf 0
    gload16(khsrc, &Kls[0][0][wv * 8][0]);
    gload16(klsrc, &Kls[0][1][wv * 8][0]);
    khsrc += (size_t)KBLK * KVD_;
    klsrc += (size_t)KBLK * KVD_;
    __syncthreads();

    for (int kt = 0; kt < ITER; kt++) {
        const int cur = kt & 1;

        // ---- phase A: issue prefetches, then compute QK^T + softmax ----
        unsigned bw[4];
#pragma unroll
        for (int r = 0; r < 4; r++) bw[r] = bptr[(size_t)r * SW_];
        bptr++;

        if (kt + 1 < ITER) {
            gload16(khsrc, &Kls[cur ^ 1][0][wv * 8][0]);
            gload16(klsrc, &Kls[cur ^ 1][1][wv * 8][0]);
            khsrc += (size_t)KBLK * KVD_;
            klsrc += (size_t)KBLK * KVD_;
        }
        gload16(vhsrc, &Vls[0][wv * 16][0]);
        gload16(vlsrc, &Vls[1][wv * 16][0]);
        vhsrc += KBLK;
        vlsrc += KBLK;

        // QK^T: 2 tiles of 16 keys from swizzled K-LDS
        f32x4 s[2];
#pragma unroll
        for (int t = 0; t < 2; t++) {
            const int row = t * 16 + lrow;
            const int sw  = row & 7;
            const bf16x8 bh0 = *(const bf16x8*)&Kls[cur][0][row][(lgrp ^ sw) * 8];
            const bf16x8 bh1 = *(const bf16x8*)&Kls[cur][0][row][((4 + lgrp) ^ sw) * 8];
            const bf16x8 bl0 = *(const bf16x8*)&Kls[cur][1][row][(lgrp ^ sw) * 8];
            const bf16x8 bl1 = *(const bf16x8*)&Kls[cur][1][row][((4 + lgrp) ^ sw) * 8];
            f32x4 acc = {0.f, 0.f, 0.f, 0.f};
            acc = MFMA(ahi[0], bh0, acc);
            acc = MFMA(alo[0], bh0, acc);
            acc = MFMA(ahi[0], bl0, acc);
            acc = MFMA(ahi[1], bh1, acc);
            acc = MFMA(alo[1], bh1, acc);
            acc = MFMA(ahi[1], bl1, acc);
            s[t] = acc;
        }

        // ---- mask + scale + row-max (C layout: row(q)=lgrp*4+r, col(key)=lrow) ----
        float tm[4];
#pragma unroll
        for (int r = 0; r < 4; r++) {
            const unsigned w = bw[r];
            const float sv0 = ((w >> lrow) & 1u)        ? s[0][r] * SCALE : NEG_BIG;
            const float sv1 = ((w >> (16 + lrow)) & 1u) ? s[1][r] * SCALE : NEG_BIG;
            s[0][r] = sv0;
            s[1][r] = sv1;
            float t = fmaxf(sv0, sv1);
            t = fmaxf(t, __shfl_xor(t, 1));
            t = fmaxf(t, __shfl_xor(t, 2));
            t = fmaxf(t, __shfl_xor(t, 4));
            t = fmaxf(t, __shfl_xor(t, 8));
            tm[r] = t;
        }

        // ---- defer-max: only rescale when some row's max grew past THR ----
        const bool small = (tm[0] <= m[0] + DEFER_THR) && (tm[1] <= m[1] + DEFER_THR) &&
                           (tm[2] <= m[2] + DEFER_THR) && (tm[3] <= m[3] + DEFER_THR);
        if (!__all(small)) {
            float fr_[4];
#pragma unroll
            for (int r = 0; r < 4; r++) {
                const float mn = fmaxf(m[r], tm[r]);
                const float f  = __expf(m[r] - mn);
                m[r] = mn;
                l[r] *= f;
                fr_[r] = f;
            }
#pragma unroll
            for (int db = 0; db < 4; db++) {
                f32x4 o = O[db];
                o[0] *= fr_[0]; o[1] *= fr_[1]; o[2] *= fr_[2]; o[3] *= fr_[3];
                O[db] = o;
            }
        }

        // ---- exp + P store + l accumulate ----
#pragma unroll
        for (int r = 0; r < 4; r++) {
            const float p0 = __expf(s[0][r] - m[r]);
            const float p1 = __expf(s[1][r] - m[r]);
            l[r] += p0 + p1;
            Pls[wv][lgrp * 4 + r][lrow]      = p0;
            Pls[wv][lgrp * 4 + r][16 + lrow] = p1;
        }
        __syncthreads();   // drains vmcnt: V(kt) + K(kt+1) staged; P visible

        // ---- phase C: PV from P-LDS (truncation hi/lo split, int-only) ----
        const f32x4 pa = *(const f32x4*)&Pls[wv][lrow][lgrp * 8];
        const f32x4 pb = *(const f32x4*)&Pls[wv][lrow][lgrp * 8 + 4];
        unsigned pu[8];
        float    pf[8];
#pragma unroll
        for (int j = 0; j < 4; j++) {
            pf[j]     = pa[j];
            pf[4 + j] = pb[j];
            pu[j]     = __builtin_bit_cast(unsigned, pa[j]);
            pu[4 + j] = __builtin_bit_cast(unsigned, pb[j]);
        }
        unsigned lu[8];
#pragma unroll
        for (int j = 0; j < 8; j++) {
            const float hf = __builtin_bit_cast(float, pu[j] & 0xFFFF0000u);
            lu[j] = __builtin_bit_cast(unsigned, pf[j] - hf);
        }
        i32x4 wh, wl;
#pragma unroll
        for (int i = 0; i < 4; i++) {
            wh[i] = (int)pack_hi16(pu[2 * i], pu[2 * i + 1]);
            wl[i] = (int)pack_hi16(lu[2 * i], lu[2 * i + 1]);
        }
        const bf16x8 ph = __builtin_bit_cast(bf16x8, wh);
        const bf16x8 pl = __builtin_bit_cast(bf16x8, wl);

#pragma unroll
        for (int db = 0; db < 4; db++) {
            const int row = db * 16 + lrow;
            const int sw  = (row >> 1) & 3;
            const bf16x8 vh = *(const bf16x8*)&Vls[0][row][(lgrp ^ sw) * 8];
            const bf16x8 vl = *(const bf16x8*)&Vls[1][row][(lgrp ^ sw) * 8];
            O[db] = MFMA(ph, vh, O[db]);
            O[db] = MFMA(pl, vh, O[db]);
            O[db] = MFMA(ph, vl, O[db]);
        }
        __syncthreads();   // Vls/Pls safe to overwrite next iteration
    }

    // ---- epilogue: reduce l across key-lanes, normalize, store ----
#pragma unroll
    for (int r = 0; r < 4; r++) {
        float lv = l[r];
        lv += __shfl_xor(lv, 1);
        lv += __shfl_xor(lv, 2);
        lv += __shfl_xor(lv, 4);
        lv += __shfl_xor(lv, 8);
        l[r] = 1.0f / lv;
    }
#pragma unroll
    for (int db = 0; db < 4; db++) {
#pragma unroll
        for (int r = 0; r < 4; r++) {
            const int q = q0 + lgrp * 4 + r;
            out[((size_t)b * S_ + q) * HD_ + h * D_ + db * 16 + lrow] = O[db][r] * l[r];
        }
    }
}

extern "C" void kernel_launch(void* const* d_in, const int* in_sizes, int n_in,
                              void* d_out, int out_size, void* d_ws, size_t ws_size,
                              hipStream_t stream) {
    const int*   mask = (const int*)d_in[0];
    const float* Q    = (const float*)d_in[1];
    const float* K    = (const float*)d_in[2];
    const float* V    = (const float*)d_in[3];
    float*       out  = (float*)d_out;

    char* ws = (char*)d_ws;
    unsigned int* bits = (unsigned int*)ws;
    const size_t KV_BYTES = (size_t)B_ * S_ * KVH_ * D_ * sizeof(__bf16);   // 2,621,440
    __bf16* khi  = (__bf16*)(ws + (1 << 20));
    __bf16* klo  = (__bf16*)(ws + (1 << 20) + KV_BYTES);
    __bf16* vthi = (__bf16*)(ws + (1 << 20) + 2 * KV_BYTES);
    __bf16* vtlo = (__bf16*)(ws + (1 << 20) + 3 * KV_BYTES);

    bitpack<<<(B_ * S_ * S_) / 256, 256, 0, stream>>>(mask, bits);
    conv_k<<<(B_ * S_ * KVH_ * D_) / (256 * 4), 256, 0, stream>>>(K, khi, klo);
    transpose_v<<<B_ * KVH_ * (S_ / 64), 256, 0, stream>>>(V, vthi, vtlo);
    attn_main<<<B_ * H_ * (S_ / 64), 256, 0, stream>>>(bits, Q, khi, klo, vthi, vtlo, out);
}

// Round 7
// 245.509 us; speedup vs baseline: 2.3311x; 1.0655x over previous
//
#include <hip/hip_runtime.h>
#include <hip/hip_bf16.h>

#define B_    2
#define S_    2048
#define H_    15
#define KVH_  5
#define G_    3
#define D_    64
#define KVD_  (KVH_ * D_)      // 320
#define HD_   (H_ * D_)        // 960
#define SW_   (S_ / 32)        // 64 mask words per row
#define KBLK  32
#define ITER  (S_ / KBLK)      // 64

constexpr float SCALE   = 0.125f;      // 64^-0.5 (exact pow2, folded into Q)
constexpr float NEG_BIG = -3.0e38f;
constexpr float DEFER_THR = 8.0f;      // defer-max rescale threshold (T13)

typedef __bf16  bf16x8 __attribute__((ext_vector_type(8)));
typedef __bf16  bf16x4 __attribute__((ext_vector_type(4)));
typedef float   f32x4  __attribute__((ext_vector_type(4)));
typedef int     i32x4  __attribute__((ext_vector_type(4)));

#define MFMA(a, b, c) __builtin_amdgcn_mfma_f32_16x16x32_bf16((a), (b), (c), 0, 0, 0)

// async global->LDS, 16B per lane; LDS dest is wave-uniform base, lane i lands at base+i*16
__device__ __forceinline__ void gload16(const void* g, void* l) {
    __builtin_amdgcn_global_load_lds(
        (const __attribute__((address_space(1))) unsigned int*)g,
        (__attribute__((address_space(3))) unsigned int*)l, 16, 0, 0);
}

// pack top-16-bits of two f32 into one bf16x2 word: low16 = trunc-bf16(e_even), high16 = trunc-bf16(e_odd)
__device__ __forceinline__ unsigned pack_hi16(unsigned even_elem, unsigned odd_elem) {
    return __builtin_amdgcn_perm(odd_elem, even_elem, 0x07060302u);
}

// ---------------- pre-pass 1: mask (int32 0/1) -> bitmask ----------------
__global__ __launch_bounds__(256) void bitpack(const int* __restrict__ mask,
                                               unsigned int* __restrict__ bits) {
    const int i = blockIdx.x * 256 + threadIdx.x;          // over B*S*S
    unsigned long long bal = __ballot(mask[i] != 0);
    const int lane = threadIdx.x & 63;
    if (lane == 0)       bits[i >> 5] = (unsigned int)bal;
    else if (lane == 32) bits[i >> 5] = (unsigned int)(bal >> 32);
}

// ---------------- pre-pass 2: K fp32 -> bf16 hi/lo (same layout) ----------------
__global__ __launch_bounds__(256) void conv_k(const float* __restrict__ K,
                                              __bf16* __restrict__ khi,
                                              __bf16* __restrict__ klo) {
    const int i = blockIdx.x * 256 + threadIdx.x;          // over (B*S*KVH*D)/4
    const float4 v = ((const float4*)K)[i];
    const float xs[4] = {v.x, v.y, v.z, v.w};
    bf16x4 h, lo;
#pragma unroll
    for (int j = 0; j < 4; j++) {
        __bf16 hh = (__bf16)xs[j];
        h[j]  = hh;
        lo[j] = (__bf16)(xs[j] - (float)hh);
    }
    ((bf16x4*)khi)[i] = h;
    ((bf16x4*)klo)[i] = lo;
}

// ---------------- pre-pass 3: V fp32 [B,S,KVH,D] -> bf16 hi/lo transposed [B,KVH,D,S] ----------------
__global__ __launch_bounds__(256) void transpose_v(const float* __restrict__ V,
                                                   __bf16* __restrict__ vthi,
                                                   __bf16* __restrict__ vtlo) {
    __shared__ float tile[64][65];
    const int bid = blockIdx.x;                 // B*KVH*(S/64)
    const int st  = bid & 31;
    const int kv  = (bid >> 5) % KVH_;
    const int b   = bid / (32 * KVH_);
    const int s0  = st * 64;
    const int tid = threadIdx.x;
    const int c   = tid & 63;
    const int rq  = tid >> 6;                   // 0..3
#pragma unroll
    for (int i = 0; i < 16; i++) {
        const int si = rq + i * 4;
        tile[si][c] = V[(((size_t)b * S_ + s0 + si) * KVH_ + kv) * D_ + c];
    }
    __syncthreads();
#pragma unroll
    for (int i = 0; i < 16; i++) {
        const int di = rq + i * 4;              // d index
        const float x = tile[c][di];            // s index = c
        const __bf16 hh = (__bf16)x;
        const size_t o = (((size_t)b * KVH_ + kv) * D_ + di) * S_ + s0 + c;
        vthi[o] = hh;
        vtlo[o] = (__bf16)(x - (float)hh);
    }
}

// ---------------- main flash-attention kernel ----------------
// grid: B*H*(S/64) blocks of 256 (4 waves); wave w handles 16 q rows, KBLK=32 keys/iter.
// SWAPPED-operand MFMAs: QK^T computes S^T=MFMA(K,Q) so each lane owns ONE q-row
// (q=lane&15) and 8 keys (16t+4*lgrp+r) -> in-register row-max, scalar m/l,
// 1 mask word/lane. PV swapped too: O^T=MFMA(V,P^T) -- V/K LDS reads unchanged.
__global__ __launch_bounds__(256) void attn_main(const unsigned int* __restrict__ bits,
                                                 const float* __restrict__ Q,
                                                 const __bf16* __restrict__ khi,
                                                 const __bf16* __restrict__ klo,
                                                 const __bf16* __restrict__ vthi,
                                                 const __bf16* __restrict__ vtlo,
                                                 float* __restrict__ out) {
    // K: [buf][hi/lo][key 0..31][d 0..63]  row=128B=8 granules, LDS[r][g]=global[r][g^(r&7)]
    // V: [hi/lo][d 0..63][key 0..31]       row=64B =4 granules, LDS[r][g]=global[r][g^((r>>1)&3)]
    // Pw: packed bf16x2 words of P^T: [wave][hi/lo][q 0..15][key-pair 0..15 +pad4]
    __shared__ __align__(16) __bf16   Kls[2][2][KBLK][64];   // 16 KB
    __shared__ __align__(16) __bf16   Vls[2][64][KBLK];      //  8 KB
    __shared__ __align__(16) unsigned Pw[4][2][16][20];      // 10 KB

    const int tid  = threadIdx.x;
    const int wv   = tid >> 6;
    const int lane = tid & 63;
    const int lrow = lane & 15;
    const int lgrp = lane >> 4;

    const int bid = blockIdx.x;
    const int qt  = bid & 31;                   // 32 q-tiles of 64
    const int bh  = bid >> 5;
    const int h   = bh % H_;
    const int b   = bh / H_;
    const int kv  = h / G_;
    const int q0  = qt * 64 + wv * 16;

    // ---- Q fragments (pre-scaled by SCALE; exact pow2 so hi/lo split unaffected) ----
    const float* qp = Q + (((size_t)b * S_ + (q0 + lrow)) * H_ + h) * D_;
    bf16x8 ahi[2], alo[2];
#pragma unroll
    for (int kk = 0; kk < 2; kk++) {
#pragma unroll
        for (int jj = 0; jj < 2; jj++) {
            const float4 v = *(const float4*)(qp + kk * 32 + lgrp * 8 + jj * 4);
            const float xs[4] = {v.x * SCALE, v.y * SCALE, v.z * SCALE, v.w * SCALE};
#pragma unroll
            for (int j = 0; j < 4; j++) {
                const __bf16 hh = (__bf16)xs[j];
                ahi[kk][jj * 4 + j] = hh;
                alo[kk][jj * 4 + j] = (__bf16)(xs[j] - (float)hh);
            }
        }
    }

    f32x4 O[4] = {{0.f,0.f,0.f,0.f},{0.f,0.f,0.f,0.f},{0.f,0.f,0.f,0.f},{0.f,0.f,0.f,0.f}};
    float m = NEG_BIG, l = 0.f;

    const __bf16* khb = khi + (size_t)b * S_ * KVD_ + kv * D_;
    const __bf16* klb = klo + (size_t)b * S_ * KVD_ + kv * D_;
    const __bf16* vhb = vthi + ((size_t)b * KVH_ + kv) * D_ * S_;
    const __bf16* vlb = vtlo + ((size_t)b * KVH_ + kv) * D_ * S_;

    // staging geometry: per gload16 a wave covers 64 granules of 16B.
    const int kgi  = wv * 64 + lane;            // K granule id over [key 0..31][gran 0..7]
    const int krow = kgi >> 3, kcg = kgi & 7;
    const int kcol = ((kcg ^ (krow & 7)) * 8);  // inverse-swizzled global d-offset
    const int vrow = kgi >> 2, vcg = kgi & 3;   // V granule id over [d 0..63][gran 0..3]
    const int vcol = ((vcg ^ ((vrow >> 1) & 3)) * 8); // inverse-swizzled global key-offset

    // running source pointers
    const __bf16* khsrc = khb + (size_t)krow * KVD_ + kcol;
    const __bf16* klsrc = klb + (size_t)krow * KVD_ + kcol;
    const __bf16* vhsrc = vhb + (size_t)vrow * S_ + vcol;
    const __bf16* vlsrc = vlb + (size_t)vrow * S_ + vcol;
    const unsigned int* bptr = bits + ((size_t)b * S_ + q0 + lrow) * SW_;   // 1 word/lane/iter

    // prologue: stage K tile 0 into buf 0
    gload16(khsrc, &Kls[0][0][wv * 8][0]);
    gload16(klsrc, &Kls[0][1][wv * 8][0]);
    khsrc += (size_t)KBLK * KVD_;
    klsrc += (size_t)KBLK * KVD_;
    __syncthreads();

    for (int kt = 0; kt < ITER; kt++) {
        const int cur = kt & 1;

        // ---- phase A: issue prefetches ----
        const unsigned w = *bptr++;             // mask word for this lane's q-row, 32 keys

        if (kt + 1 < ITER) {
            gload16(khsrc, &Kls[cur ^ 1][0][wv * 8][0]);
            gload16(klsrc, &Kls[cur ^ 1][1][wv * 8][0]);
            khsrc += (size_t)KBLK * KVD_;
            klsrc += (size_t)KBLK * KVD_;
        }
        gload16(vhsrc, &Vls[0][wv * 16][0]);
        gload16(vlsrc, &Vls[1][wv * 16][0]);
        vhsrc += KBLK;
        vlsrc += KBLK;

        // ---- QK^T (swapped): S^T[key][q] = MFMA(K, Q); lane -> q=lrow, key=16t+4*lgrp+r ----
        f32x4 s[2];
#pragma unroll
        for (int t = 0; t < 2; t++) {
            const int row = t * 16 + lrow;
            const int sw  = row & 7;
            const bf16x8 bh0 = *(const bf16x8*)&Kls[cur][0][row][(lgrp ^ sw) * 8];
            const bf16x8 bh1 = *(const bf16x8*)&Kls[cur][0][row][((4 + lgrp) ^ sw) * 8];
            const bf16x8 bl0 = *(const bf16x8*)&Kls[cur][1][row][(lgrp ^ sw) * 8];
            const bf16x8 bl1 = *(const bf16x8*)&Kls[cur][1][row][((4 + lgrp) ^ sw) * 8];
            f32x4 acc = {0.f, 0.f, 0.f, 0.f};
            acc = MFMA(bh0, ahi[0], acc);
            acc = MFMA(bh0, alo[0], acc);
            acc = MFMA(bl0, ahi[0], acc);
            acc = MFMA(bh1, ahi[1], acc);
            acc = MFMA(bh1, alo[1], acc);
            acc = MFMA(bl1, ahi[1], acc);
            s[t] = acc;
        }

        // ---- mask + in-register row-max (7 fmax) + 2 shfl ----
        float pmax = NEG_BIG;
#pragma unroll
        for (int t = 0; t < 2; t++) {
#pragma unroll
            for (int r = 0; r < 4; r++) {
                const int bit = t * 16 + lgrp * 4 + r;
                const float sv = ((w >> bit) & 1u) ? s[t][r] : NEG_BIG;
                s[t][r] = sv;
                pmax = fmaxf(pmax, sv);
            }
        }
        pmax = fmaxf(pmax, __shfl_xor(pmax, 16));
        pmax = fmaxf(pmax, __shfl_xor(pmax, 32));

        // ---- defer-max: rescale only when some row's max grew past THR ----
        if (!__all(pmax <= m + DEFER_THR)) {
            const float mn = fmaxf(m, pmax);
            const float f  = __expf(m - mn);
            m = mn;
            l *= f;
#pragma unroll
            for (int db = 0; db < 4; db++) {
                f32x4 o = O[db];
                o[0] *= f; o[1] *= f; o[2] *= f; o[3] *= f;
                O[db] = o;
            }
        }

        // ---- exp + split/pack + P^T store (4 ds_write_b64) ----
#pragma unroll
        for (int t = 0; t < 2; t++) {
            unsigned words[2][2];               // [hi/lo][pair]
#pragma unroll
            for (int pr = 0; pr < 2; pr++) {
                const float e0 = __expf(s[t][2 * pr]     - m);
                const float e1 = __expf(s[t][2 * pr + 1] - m);
                l += e0 + e1;
                const unsigned u0 = __builtin_bit_cast(unsigned, e0);
                const unsigned u1 = __builtin_bit_cast(unsigned, e1);
                const float h0 = __builtin_bit_cast(float, u0 & 0xFFFF0000u);
                const float h1 = __builtin_bit_cast(float, u1 & 0xFFFF0000u);
                const unsigned l0 = __builtin_bit_cast(unsigned, e0 - h0);
                const unsigned l1 = __builtin_bit_cast(unsigned, e1 - h1);
                words[0][pr] = pack_hi16(u0, u1);
                words[1][pr] = pack_hi16(l0, l1);
            }
            // key-pair index kp = 8t + 2*lgrp + pr  -> write pairs as one b64
            *(uint2*)&Pw[wv][0][lrow][8 * t + 2 * lgrp] = make_uint2(words[0][0], words[0][1]);
            *(uint2*)&Pw[wv][1][lrow][8 * t + 2 * lgrp] = make_uint2(words[1][0], words[1][1]);
        }
        __syncthreads();   // drains vmcnt: V(kt) + K(kt+1) staged; P^T visible

        // ---- phase C: PV (swapped): O^T[d][q] = MFMA(V^T, P^T) ----
        const bf16x8 ph = __builtin_bit_cast(bf16x8, *(const i32x4*)&Pw[wv][0][lrow][lgrp * 4]);
        const bf16x8 pl = __builtin_bit_cast(bf16x8, *(const i32x4*)&Pw[wv][1][lrow][lgrp * 4]);
#pragma unroll
        for (int db = 0; db < 4; db++) {
            const int row = db * 16 + lrow;
            const int sw  = (row >> 1) & 3;
            const bf16x8 vh = *(const bf16x8*)&Vls[0][row][(lgrp ^ sw) * 8];
            const bf16x8 vl = *(const bf16x8*)&Vls[1][row][(lgrp ^ sw) * 8];
            O[db] = MFMA(vh, ph, O[db]);
            O[db] = MFMA(vh, pl, O[db]);
            O[db] = MFMA(vl, ph, O[db]);
        }
        __syncthreads();   // Vls/Pw safe to overwrite next iteration
    }

    // ---- epilogue: sum l across the 4 key-replicas, normalize, float4 stores ----
    float lv = l;
    lv += __shfl_xor(lv, 16);
    lv += __shfl_xor(lv, 32);
    const float inv = 1.0f / lv;
    float* op = out + ((size_t)b * S_ + q0 + lrow) * HD_ + h * D_ + lgrp * 4;
#pragma unroll
    for (int db = 0; db < 4; db++) {
        f32x4 o = O[db];
        o[0] *= inv; o[1] *= inv; o[2] *= inv; o[3] *= inv;
        *(f32x4*)(op + db * 16) = o;           // d = db*16 + lgrp*4 + reg
    }
}

extern "C" void kernel_launch(void* const* d_in, const int* in_sizes, int n_in,
                              void* d_out, int out_size, void* d_ws, size_t ws_size,
                              hipStream_t stream) {
    const int*   mask = (const int*)d_in[0];
    const float* Q    = (const float*)d_in[1];
    const float* K    = (const float*)d_in[2];
    const float* V    = (const float*)d_in[3];
    float*       out  = (float*)d_out;

    char* ws = (char*)d_ws;
    unsigned int* bits = (unsigned int*)ws;
    const size_t KV_BYTES = (size_t)B_ * S_ * KVH_ * D_ * sizeof(__bf16);   // 2,621,440
    __bf16* khi  = (__bf16*)(ws + (1 << 20));
    __bf16* klo  = (__bf16*)(ws + (1 << 20) + KV_BYTES);
    __bf16* vthi = (__bf16*)(ws + (1 << 20) + 2 * KV_BYTES);
    __bf16* vtlo = (__bf16*)(ws + (1 << 20) + 3 * KV_BYTES);

    bitpack<<<(B_ * S_ * S_) / 256, 256, 0, stream>>>(mask, bits);
    conv_k<<<(B_ * S_ * KVH_ * D_) / (256 * 4), 256, 0, stream>>>(K, khi, klo);
    transpose_v<<<B_ * KVH_ * (S_ / 64), 256, 0, stream>>>(V, vthi, vtlo);
    attn_main<<<B_ * H_ * (S_ / 64), 256, 0, stream>>>(bits, Q, khi, klo, vthi, vtlo, out);
}

// Round 11
// 232.396 us; speedup vs baseline: 2.4626x; 1.0564x over previous
//
#include <hip/hip_runtime.h>
#include <hip/hip_bf16.h>

#define B_    2
#define S_    2048
#define H_    15
#define KVH_  5
#define G_    3
#define D_    64
#define KVD_  (KVH_ * D_)      // 320
#define HD_   (H_ * D_)        // 960
#define SW_   (S_ / 32)        // 64 mask words per row
#define KBLK  32
#define ITER  (S_ / KBLK)      // 64

constexpr float SCALE   = 0.125f;      // 64^-0.5 (exact pow2, folded into Q)
constexpr float NEG_BIG = -3.0e38f;
constexpr float DEFER_THR = 8.0f;      // defer-max rescale threshold (T13)

typedef __bf16  bf16x8 __attribute__((ext_vector_type(8)));
typedef __bf16  bf16x4 __attribute__((ext_vector_type(4)));
typedef float   f32x4  __attribute__((ext_vector_type(4)));
typedef int     i32x4  __attribute__((ext_vector_type(4)));

#define MFMA(a, b, c) __builtin_amdgcn_mfma_f32_16x16x32_bf16((a), (b), (c), 0, 0, 0)

// async global->LDS, 16B per lane; LDS dest is wave-uniform base, lane i lands at base+i*16
__device__ __forceinline__ void gload16(const void* g, void* l) {
    __builtin_amdgcn_global_load_lds(
        (const __attribute__((address_space(1))) unsigned int*)g,
        (__attribute__((address_space(3))) unsigned int*)l, 16, 0, 0);
}

// pack top-16-bits of two f32 into one bf16x2 word: low16 = trunc-bf16(even), high16 = trunc-bf16(odd)
__device__ __forceinline__ unsigned pack_hi16(unsigned even_elem, unsigned odd_elem) {
    return __builtin_amdgcn_perm(odd_elem, even_elem, 0x07060302u);
}

// ---------------- pre-pass 1: mask (int32 0/1) -> bitmask (grid-stride, 2048 wgs) ----------------
__global__ __launch_bounds__(256) void bitpack(const int* __restrict__ mask,
                                               unsigned int* __restrict__ bits) {
    const int stride = gridDim.x * 256;
    const int lane   = threadIdx.x & 63;
    for (int i = blockIdx.x * 256 + threadIdx.x; i < B_ * S_ * S_; i += stride) {
        unsigned long long bal = __ballot(mask[i] != 0);
        if (lane == 0)       bits[i >> 5] = (unsigned int)bal;
        else if (lane == 32) bits[i >> 5] = (unsigned int)(bal >> 32);
    }
}

// ---------------- pre-pass 2: K fp32 -> bf16 hi/lo (same layout) ----------------
__global__ __launch_bounds__(256) void conv_k(const float* __restrict__ K,
                                              __bf16* __restrict__ khi,
                                              __bf16* __restrict__ klo) {
    const int i = blockIdx.x * 256 + threadIdx.x;          // over (B*S*KVH*D)/4
    const float4 v = ((const float4*)K)[i];
    const float xs[4] = {v.x, v.y, v.z, v.w};
    bf16x4 h, lo;
#pragma unroll
    for (int j = 0; j < 4; j++) {
        __bf16 hh = (__bf16)xs[j];
        h[j]  = hh;
        lo[j] = (__bf16)(xs[j] - (float)hh);
    }
    ((bf16x4*)khi)[i] = h;
    ((bf16x4*)klo)[i] = lo;
}

// ---------------- pre-pass 3: V fp32 [B,S,KVH,D] -> bf16 hi/lo transposed [B,KVH,D,S] ----------------
// 512 threads/block (8 waves) for latency hiding; 320 blocks.
__global__ __launch_bounds__(512) void transpose_v(const float* __restrict__ V,
                                                   __bf16* __restrict__ vthi,
                                                   __bf16* __restrict__ vtlo) {
    __shared__ float tile[64][65];
    const int bid = blockIdx.x;                 // B*KVH*(S/64)
    const int st  = bid & 31;
    const int kv  = (bid >> 5) % KVH_;
    const int b   = bid / (32 * KVH_);
    const int s0  = st * 64;
    const int tid = threadIdx.x;
    const int c   = tid & 63;
    const int rq  = tid >> 6;                   // 0..7
#pragma unroll
    for (int i = 0; i < 8; i++) {
        const int si = rq + i * 8;
        tile[si][c] = V[(((size_t)b * S_ + s0 + si) * KVH_ + kv) * D_ + c];
    }
    __syncthreads();
#pragma unroll
    for (int i = 0; i < 8; i++) {
        const int di = rq + i * 8;              // d index
        const float x = tile[c][di];            // s index = c
        const __bf16 hh = (__bf16)x;
        const size_t o = (((size_t)b * KVH_ + kv) * D_ + di) * S_ + s0 + c;
        vthi[o] = hh;
        vtlo[o] = (__bf16)(x - (float)hh);
    }
}

// ---------------- main flash-attention kernel ----------------
// grid: B*H*(S/64) blocks of 256 (4 waves); wave w handles 16 q rows, KBLK=32 keys/iter.
// Swapped-operand MFMAs (S^T = MFMA(K,Q), O^T = MFMA(V,P)).
// KEY-PERMUTED K staging: LDS K row rho holds global key sigma(rho)=8*((rho>>2)&3)+4*(rho>>4)+(rho&3),
// so QK^T's C-layout (key-row = 16t+4*lgrp+r) leaves each lane holding keys 8*lgrp+4t+r —
// exactly the 8 consecutive keys PV's B-operand needs. P stays entirely in registers.
// K and V both double-buffered -> ONE barrier per iteration.
__global__ __launch_bounds__(256) void attn_main(const unsigned int* __restrict__ bits,
                                                 const float* __restrict__ Q,
                                                 const __bf16* __restrict__ khi,
                                                 const __bf16* __restrict__ klo,
                                                 const __bf16* __restrict__ vthi,
                                                 const __bf16* __restrict__ vtlo,
                                                 float* __restrict__ out) {
    // K: [buf][hi/lo][row 0..31][d 0..63]  row=128B=8 granules, LDS[r][g]=globalkey sigma(r)[g^(r&7)]
    // V: [buf][hi/lo][d 0..63][key 0..31]  row=64B =4 granules, LDS[r][g]=global[r][g^((r>>1)&3)]
    __shared__ __align__(16) __bf16 Kls[2][2][KBLK][64];   // 16 KB
    __shared__ __align__(16) __bf16 Vls[2][2][64][KBLK];   // 16 KB

    const int tid  = threadIdx.x;
    const int wv   = tid >> 6;
    const int lane = tid & 63;
    const int lrow = lane & 15;
    const int lgrp = lane >> 4;

    const int bid = blockIdx.x;
    const int qt  = bid & 31;                   // 32 q-tiles of 64
    const int bh  = bid >> 5;
    const int h   = bh % H_;
    const int b   = bh / H_;
    const int kv  = h / G_;
    const int q0  = qt * 64 + wv * 16;

    // ---- Q fragments (pre-scaled by SCALE; exact pow2 so hi/lo split unaffected) ----
    const float* qp = Q + (((size_t)b * S_ + (q0 + lrow)) * H_ + h) * D_;
    bf16x8 ahi[2], alo[2];
#pragma unroll
    for (int kk = 0; kk < 2; kk++) {
#pragma unroll
        for (int jj = 0; jj < 2; jj++) {
            const float4 v = *(const float4*)(qp + kk * 32 + lgrp * 8 + jj * 4);
            const float xs[4] = {v.x * SCALE, v.y * SCALE, v.z * SCALE, v.w * SCALE};
#pragma unroll
            for (int j = 0; j < 4; j++) {
                const __bf16 hh = (__bf16)xs[j];
                ahi[kk][jj * 4 + j] = hh;
                alo[kk][jj * 4 + j] = (__bf16)(xs[j] - (float)hh);
            }
        }
    }

    f32x4 O[4] = {{0.f,0.f,0.f,0.f},{0.f,0.f,0.f,0.f},{0.f,0.f,0.f,0.f},{0.f,0.f,0.f,0.f}};
    float m = NEG_BIG, l = 0.f;

    const __bf16* khb = khi + (size_t)b * S_ * KVD_ + kv * D_;
    const __bf16* klb = klo + (size_t)b * S_ * KVD_ + kv * D_;
    const __bf16* vhb = vthi + ((size_t)b * KVH_ + kv) * D_ * S_;
    const __bf16* vlb = vtlo + ((size_t)b * KVH_ + kv) * D_ * S_;

    // staging geometry: per gload16 a wave covers 64 granules of 16B.
    // K: LDS row rho = 8*wv + (lane>>3); source key = sigma(rho); col granule inverse-swizzled.
    const int kgi  = wv * 64 + lane;
    const int krho = kgi >> 3;                              // LDS row 0..31
    const int kkey = 8 * ((krho >> 2) & 3) + 4 * (krho >> 4) + (krho & 3);   // permuted key
    const int kcol = (((kgi & 7) ^ (krho & 7)) * 8);        // inverse-swizzled d-offset
    const int vrow = kgi >> 2, vcg = kgi & 3;               // V granule over [d 0..63][gran 0..3]
    const int vcol = ((vcg ^ ((vrow >> 1) & 3)) * 8);       // inverse-swizzled key-offset

    // running source pointers
    const __bf16* khsrc = khb + (size_t)kkey * KVD_ + kcol;
    const __bf16* klsrc = klb + (size_t)kkey * KVD_ + kcol;
    const __bf16* vhsrc = vhb + (size_t)vrow * S_ + vcol;
    const __bf16* vlsrc = vlb + (size_t)vrow * S_ + vcol;
    const unsigned int* bptr = bits + ((size_t)b * S_ + q0 + lrow) * SW_;   // 1 word/lane/iter

    // prologue: stage K[0], V[0] into buf 0
    gload16(khsrc, &Kls[0][0][wv * 8][0]);
    gload16(klsrc, &Kls[0][1][wv * 8][0]);
    gload16(vhsrc, &Vls[0][0][wv * 16][0]);
    gload16(vlsrc, &Vls[0][1][wv * 16][0]);
    khsrc += (size_t)KBLK * KVD_;
    klsrc += (size_t)KBLK * KVD_;
    vhsrc += KBLK;
    vlsrc += KBLK;
    __syncthreads();

    for (int kt = 0; kt < ITER; kt++) {
        const int cur = kt & 1;

        // ---- issue next-tile prefetches (land by the end-of-iter barrier) ----
        const unsigned w = *bptr++;             // mask word: this lane's q-row, keys of this tile

        if (kt + 1 < ITER) {
            gload16(khsrc, &Kls[cur ^ 1][0][wv * 8][0]);
            gload16(klsrc, &Kls[cur ^ 1][1][wv * 8][0]);
            gload16(vhsrc, &Vls[cur ^ 1][0][wv * 16][0]);
            gload16(vlsrc, &Vls[cur ^ 1][1][wv * 16][0]);
            khsrc += (size_t)KBLK * KVD_;
            klsrc += (size_t)KBLK * KVD_;
            vhsrc += KBLK;
            vlsrc += KBLK;
        }

        // ---- QK^T (swapped): lane ends with s[t][r] = S[key=8*lgrp+4t+r][q=lrow] ----
        f32x4 s[2];
#pragma unroll
        for (int t = 0; t < 2; t++) {
            const int row = t * 16 + lrow;
            const int sw  = row & 7;
            const bf16x8 bh0 = *(const bf16x8*)&Kls[cur][0][row][(lgrp ^ sw) * 8];
            const bf16x8 bh1 = *(const bf16x8*)&Kls[cur][0][row][((4 + lgrp) ^ sw) * 8];
            const bf16x8 bl0 = *(const bf16x8*)&Kls[cur][1][row][(lgrp ^ sw) * 8];
            const bf16x8 bl1 = *(const bf16x8*)&Kls[cur][1][row][((4 + lgrp) ^ sw) * 8];
            f32x4 acc = {0.f, 0.f, 0.f, 0.f};
            acc = MFMA(bh0, ahi[0], acc);
            acc = MFMA(bh0, alo[0], acc);
            acc = MFMA(bl0, ahi[0], acc);
            acc = MFMA(bh1, ahi[1], acc);
            acc = MFMA(bh1, alo[1], acc);
            acc = MFMA(bl1, ahi[1], acc);
            s[t] = acc;
        }

        // ---- mask + in-register row-max; key bit = 8*lgrp + 4t + r ----
        float pmax = NEG_BIG;
#pragma unroll
        for (int t = 0; t < 2; t++) {
#pragma unroll
            for (int r = 0; r < 4; r++) {
                const int bit = 8 * lgrp + 4 * t + r;
                const float sv = ((w >> bit) & 1u) ? s[t][r] : NEG_BIG;
                s[t][r] = sv;
                pmax = fmaxf(pmax, sv);
            }
        }
        pmax = fmaxf(pmax, __shfl_xor(pmax, 16));
        pmax = fmaxf(pmax, __shfl_xor(pmax, 32));

        // ---- defer-max: rescale only when some row's max grew past THR ----
        if (!__all(pmax <= m + DEFER_THR)) {
            const float mn = fmaxf(m, pmax);
            const float f  = __expf(m - mn);
            m = mn;
            l *= f;
#pragma unroll
            for (int db = 0; db < 4; db++) {
                f32x4 o = O[db];
                o[0] *= f; o[1] *= f; o[2] *= f; o[3] *= f;
                O[db] = o;
            }
        }

        // ---- exp + in-register split/pack: word w' covers keys 8*lgrp+2w' ----
        unsigned hw[4], lw[4];
#pragma unroll
        for (int t = 0; t < 2; t++) {
#pragma unroll
            for (int pr = 0; pr < 2; pr++) {
                const float e0 = __expf(s[t][2 * pr]     - m);
                const float e1 = __expf(s[t][2 * pr + 1] - m);
                l += e0 + e1;
                const unsigned u0 = __builtin_bit_cast(unsigned, e0);
                const unsigned u1 = __builtin_bit_cast(unsigned, e1);
                const float h0 = __builtin_bit_cast(float, u0 & 0xFFFF0000u);
                const float h1 = __builtin_bit_cast(float, u1 & 0xFFFF0000u);
                const unsigned l0 = __builtin_bit_cast(unsigned, e0 - h0);
                const unsigned l1 = __builtin_bit_cast(unsigned, e1 - h1);
                hw[2 * t + pr] = pack_hi16(u0, u1);
                lw[2 * t + pr] = pack_hi16(l0, l1);
            }
        }
        i32x4 wh, wl;
#pragma unroll
        for (int i = 0; i < 4; i++) { wh[i] = (int)hw[i]; wl[i] = (int)lw[i]; }
        const bf16x8 ph = __builtin_bit_cast(bf16x8, wh);
        const bf16x8 pl = __builtin_bit_cast(bf16x8, wl);

        // ---- PV (swapped): O^T[d][q] = MFMA(V, P); P is in-register ----
#pragma unroll
        for (int db = 0; db < 4; db++) {
            const int row = db * 16 + lrow;
            const int sw  = (row >> 1) & 3;
            const bf16x8 vh = *(const bf16x8*)&Vls[cur][0][row][(lgrp ^ sw) * 8];
            const bf16x8 vl = *(const bf16x8*)&Vls[cur][1][row][(lgrp ^ sw) * 8];
            O[db] = MFMA(vh, ph, O[db]);
            O[db] = MFMA(vh, pl, O[db]);
            O[db] = MFMA(vl, ph, O[db]);
        }

        __syncthreads();   // single barrier: drains prefetch vmcnt; fences buf reuse
    }

    // ---- epilogue: sum l across the 4 key-replicas, normalize, float4 stores ----
    float lv = l;
    lv += __shfl_xor(lv, 16);
    lv += __shfl_xor(lv, 32);
    const float inv = 1.0f / lv;
    float* op = out + ((size_t)b * S_ + q0 + lrow) * HD_ + h * D_ + lgrp * 4;
#pragma unroll
    for (int db = 0; db < 4; db++) {
        f32x4 o = O[db];
        o[0] *= inv; o[1] *= inv; o[2] *= inv; o[3] *= inv;
        *(f32x4*)(op + db * 16) = o;           // d = db*16 + lgrp*4 + reg
    }
}

extern "C" void kernel_launch(void* const* d_in, const int* in_sizes, int n_in,
                              void* d_out, int out_size, void* d_ws, size_t ws_size,
                              hipStream_t stream) {
    const int*   mask = (const int*)d_in[0];
    const float* Q    = (const float*)d_in[1];
    const float* K    = (const float*)d_in[2];
    const float* V    = (const float*)d_in[3];
    float*       out  = (float*)d_out;

    char* ws = (char*)d_ws;
    unsigned int* bits = (unsigned int*)ws;
    const size_t KV_BYTES = (size_t)B_ * S_ * KVH_ * D_ * sizeof(__bf16);   // 2,621,440
    __bf16* khi  = (__bf16*)(ws + (1 << 20));
    __bf16* klo  = (__bf16*)(ws + (1 << 20) + KV_BYTES);
    __bf16* vthi = (__bf16*)(ws + (1 << 20) + 2 * KV_BYTES);
    __bf16* vtlo = (__bf16*)(ws + (1 << 20) + 3 * KV_BYTES);

    bitpack<<<2048, 256, 0, stream>>>(mask, bits);
    conv_k<<<(B_ * S_ * KVH_ * D_) / (256 * 4), 256, 0, stream>>>(K, khi, klo);
    transpose_v<<<B_ * KVH_ * (S_ / 64), 512, 0, stream>>>(V, vthi, vtlo);
    attn_main<<<B_ * H_ * (S_ / 64), 256, 0, stream>>>(bits, Q, khi, klo, vthi, vtlo, out);
}